// Round 12
// baseline (227.820 us; speedup 1.0000x reference)
//
#include <hip/hip_runtime.h>
#include <math.h>

#define T_STEPS 32
#define NB 64      // batch
#define CC 512     // channels
#define AA 32      // cc_acc size
#define MROWS (T_STEPS * NB)   // 2048 GEMM rows

typedef __attribute__((ext_vector_type(8)))  short bf16x8;
typedef __attribute__((ext_vector_type(16))) float f32x16;

__device__ __forceinline__ float sig_decay(const float* wp) {
    return 1.0f - 1.0f / (1.0f + expf(-wp[0]));   // 1 - sigmoid(w)
}

__device__ __forceinline__ unsigned short f2bf_rne(float f) {
    unsigned int u = __float_as_uint(f);
    u += 0x7FFF + ((u >> 16) & 1);
    return (unsigned short)(u >> 16);
}

// ===========================================================================
// Packed-operand layouts (verified by rounds 5-11 passing runs):
//   A/B fragment chunk (16 B = 8 bf16): lane L holds row r = (L&31) of a
//   32-row tile, k = 8*(L>>5) + j.  Chunk index:
//     A: (mt*KS + ks)*64 + L          mt = m>>5, ks = k>>4, KS = K/16
//     B: ((p*NT + nt)*KS + ks)*64 + L nt = n>>5, NT = N/32, p = plane
//   C tile (32x32 fp32, row-major): idx = (mt*NT + nt)*1024 + row*32 + col
// ===========================================================================

// ---------------------------------------------------------------------------
// Split ALL three weight matrices into 3 bf16 planes (hi/mid/lo) packed in
// B-fragment order.  One fused launch.
// ---------------------------------------------------------------------------
#define NW1 (2048 * 512)
#define NW2 (1024 * 2048)
#define NW3 (512 * 1024)

__device__ __forceinline__ void pack_one(
    const float* __restrict__ W, unsigned short* __restrict__ out,
    int idx, int Nw, int Kw, int kshift)
{
    int n = idx >> kshift;
    int k = idx & (Kw - 1);
    float w = W[idx];
    unsigned short h = f2bf_rne(w);
    float fh = __uint_as_float((unsigned int)h << 16);
    float r = w - fh;
    unsigned short m = f2bf_rne(r);
    float fm = __uint_as_float((unsigned int)m << 16);
    unsigned short l = f2bf_rne(r - fm);
    unsigned short vals[3] = {h, m, l};
    const int NT = Nw >> 5, KS = Kw >> 4;
    int L = (n & 31) + 32 * ((k >> 3) & 1);
#pragma unroll
    for (int p = 0; p < 3; p++) {
        size_t chunk = ((size_t)(p * NT + (n >> 5)) * KS + (k >> 4)) * 64 + L;
        out[chunk * 8 + (k & 7)] = vals[p];
    }
}

__global__ __launch_bounds__(256) void pack_all_kernel(
    const float* __restrict__ W1, const float* __restrict__ W2,
    const float* __restrict__ W3,
    unsigned short* __restrict__ B1, unsigned short* __restrict__ B2,
    unsigned short* __restrict__ B3)
{
    int i = blockIdx.x * 256 + threadIdx.x;
    if (i < NW1) {
        pack_one(W1, B1, i, 2048, 512, 9);
    } else if (i < NW1 + NW2) {
        pack_one(W2, B2, i - NW1, 1024, 2048, 11);
    } else if (i < NW1 + NW2 + NW3) {
        pack_one(W3, B3, i - NW1 - NW2, 512, 1024, 10);
    }
}

// ---------------------------------------------------------------------------
// Front end (transpose + synapse tau=2 + jeffress + LIF + sf0 + w_cc + IF).
// spike_out != null: write IF spikes in packed A-fragment order (K = 512).
// ---------------------------------------------------------------------------
__global__ __launch_bounds__(256) void front_kernel(
    const float* __restrict__ x, const float* __restrict__ w_jeff,
    const float* __restrict__ w_cc, const float* __restrict__ w_sf0,
    const float* __restrict__ w_sf1,
    unsigned short* __restrict__ spike_out, float* __restrict__ filt_out)
{
    __shared__ float wj[2 * AA];
    __shared__ float wcc[AA];
    int tid = threadIdx.x;
    if (tid < 2 * AA) wj[tid] = w_jeff[tid];
    if (tid < AA) wcc[tid] = w_cc[tid];
    __syncthreads();

    int g = blockIdx.x * 256 + tid;     // n*CC + c
    int n = g >> 9;
    int c = g & (CC - 1);

    const float inv_lif = 1.0f / 1.5f;
    float d0 = sig_decay(w_sf0);
    float d1 = sig_decay(w_sf1);

    float s0 = 0.f, s1 = 0.f, v6 = 0.f, u1 = 0.f;
    float v[AA], u[AA];
#pragma unroll
    for (int a = 0; a < AA; a++) { v[a] = 0.f; u[a] = 0.f; }

    const int pL = (n & 31) + 32 * ((c >> 3) & 1);
    const int pks = c >> 4;
    const int pj = c & 7;

    for (int t = 0; t < T_STEPS; t++) {
        const float* xp = x + (size_t)((t * NB + n) * 2) * CC + c;
        s0 = s0 * 0.5f + xp[0];
        s1 = s1 * 0.5f + xp[CC];
        float acc = 0.f;
#pragma unroll
        for (int a = 0; a < AA; a++) {
            float z  = wj[2 * a] * s0 + wj[2 * a + 1] * s1;
            float vv = v[a] + (z - v[a]) * inv_lif;
            bool  sp = vv >= 1.0f;
            v[a] = sp ? 0.0f : vv;
            float uu = u[a] * d0 + (sp ? 1.0f : 0.0f);
            u[a] = uu;
            acc += wcc[a] * uu;
        }
        v6 += acc;
        bool sp6 = v6 >= 1.0f;
        v6 = sp6 ? 0.0f : v6;
        if (spike_out) {
            int mt = (t * NB + n) >> 5;
            size_t adr = (((size_t)mt * 32 + pks) * 64 + pL) * 8 + pj;
            spike_out[adr] = sp6 ? (unsigned short)0x3F80 : (unsigned short)0;
        } else {
            u1 = u1 * d1 + (sp6 ? 1.0f : 0.0f);
            filt_out[(size_t)(t * NB + n) * CC + c] = u1;
        }
    }
}

// ---------------------------------------------------------------------------
// Consumer (round-10 proven): sum NPARTS split-K parts, commuted filter,
// IF, emit spikes.  Double-buffered register tiles + sched_barrier fences.
// ---------------------------------------------------------------------------
template <int NPARTS>
__global__ __launch_bounds__(256) void if_spike_kernel(
    const float* __restrict__ G, size_t partStride,
    const float* __restrict__ w_sf_in, int F, int fshift,
    unsigned short* __restrict__ out_bf, float* __restrict__ out_f32)
{
    constexpr int TT = 16 / NPARTS;           // t's per tile (16 / 8 / 4)
    constexpr int NTILES = T_STEPS / TT;      // 2 / 4 / 8

    int gid = blockIdx.x * 256 + threadIdx.x;   // n*F + f
    int n = gid >> fshift;
    int f = gid & (F - 1);
    const int NT = F >> 5;
    const int NF = NB * F;
    float dz = sig_decay(w_sf_in);

    size_t base = ((size_t)(n >> 5) * NT + (f >> 5)) * 1024
                + (size_t)(n & 31) * 32 + (f & 31);
    const size_t tstride = (size_t)2 * NT * 1024;

    float buf[2][NPARTS][TT];
    auto pf = [&](int b, int tile) {
#pragma unroll
        for (int p = 0; p < NPARTS; p++)
#pragma unroll
            for (int j = 0; j < TT; j++)
                buf[b][p][j] = G[(size_t)p * partStride + base
                               + (size_t)(tile * TT + j) * tstride];
    };

    const int pL = (n & 31) + 32 * ((f >> 3) & 1);
    const int KS = F >> 4;

    pf(0, 0);
    float zf = 0.f, v = 0.f;
#pragma unroll
    for (int tile = 0; tile < NTILES; tile++) {
        const int b = tile & 1;
        if (tile + 1 < NTILES) pf(b ^ 1, tile + 1);   // prefetch next tile
        __builtin_amdgcn_sched_barrier(0);            // pin loads above
#pragma unroll
        for (int j = 0; j < TT; j++) {
            int t = tile * TT + j;
            float gsum = buf[b][0][j];
#pragma unroll
            for (int p = 1; p < NPARTS; p++) gsum += buf[b][p][j];
            zf = zf * dz + gsum;      // commuted synapse filter
            v += zf;                  // IF
            bool sp = v >= 1.0f;
            v = sp ? 0.0f : v;
            if (out_bf) {
                int mt = 2 * t + (n >> 5);
                size_t adr = (((size_t)mt * KS + (f >> 4)) * 64 + pL) * 8 + (f & 7);
                out_bf[adr] = sp ? (unsigned short)0x3F80 : (unsigned short)0;
            } else {
                out_f32[(size_t)t * NF + gid] = sp ? 1.0f : 0.0f;
            }
        }
        __builtin_amdgcn_sched_barrier(0);            // pin recurrence above
    }
}

// ---------------------------------------------------------------------------
// Binary-A bf16 MFMA GEMM v3.  128x128 block tile, 512 threads = 8 waves =
// 4 spatial n-tiles x 2 k-groups.  Group g handles k-stages ks0 + 2s + g
// with its own A-LDS double buffer (total 16 KB) and per-wave B registers
// (double-buffered, lookahead = 4 k-stages; literal buffer indices via the
// macro-expanded stage pair).  End: g1 accs added into g0 via LDS (fixed
// order -> deterministic), halving the EXTERNAL split-K count vs v2 with
// identical wave occupancy (8 waves/CU = 2/SIMD).  nk2 = K_per/32 even.
// ---------------------------------------------------------------------------
__global__ __launch_bounds__(512, 2) void bgemm(
    const unsigned short* __restrict__ Ap,   // packed spikes (M x K)
    const unsigned short* __restrict__ Bp,   // packed 3-plane weights
    float* __restrict__ C,                   // sk partials, tiled
    int N, int K_total, int K_per)
{
    const int NT = N >> 5, KS = K_total >> 4;
    __shared__ bf16x8 shA[2][2][256];        // [group][buf][chunk] = 16 KB

    const int tid = threadIdx.x;
    const int g   = tid >> 8;                // k-group 0/1
    const int lt  = tid & 255;               // thread index within group
    const int sn  = (tid >> 6) & 3;          // n-tile of this wave (0..3)
    const int L   = tid & 63;
    const int bm32 = blockIdx.x * 4;         // 4 m-tiles (128 m)
    const int bn32 = blockIdx.y * 4;         // 4 n-tiles (128 n)
    const int ks0  = (blockIdx.z * K_per) >> 4;
    const int nk2  = K_per >> 5;             // group-stages (8/16/32 -> even)

    f32x16 acc[4];
#pragma unroll
    for (int i = 0; i < 4; i++)
#pragma unroll
        for (int r = 0; r < 16; r++) acc[i][r] = 0.f;

    const bf16x8* A8 = (const bf16x8*)Ap;
    const bf16x8* B8 = (const bf16x8*)Bp;

    bf16x8 pa;                               // A staging reg (1 chunk/thread)
    auto gloadA = [&](int s) {
        pa = A8[((size_t)(bm32 + (lt >> 6)) * KS + ks0 + 2 * s + g) * 64 + (lt & 63)];
    };
    auto lwriteA = [&](int b) { shA[g][b][lt] = pa; };

    bf16x8 pb0[3], pb1[3];                   // B double buffer (literal idx)
    auto gloadB = [&](int s, bf16x8* pbuf) {
#pragma unroll
        for (int p = 0; p < 3; p++)
            pbuf[p] = B8[((size_t)(p * NT + bn32 + sn) * KS + ks0 + 2 * s + g) * 64 + L];
    };

    bf16x8 af[4];
    auto rfragsA = [&](int b) {
#pragma unroll
        for (int i = 0; i < 4; i++)
            af[i] = shA[g][b][i * 64 + L];
    };

    // prologue: group-stage 0 in shA[g][0]/pb0, group-stage 1 in pa/pb1
    gloadA(0);
    gloadB(0, pb0);
    lwriteA(0);
    gloadA(1);
    gloadB(1, pb1);
    __syncthreads();
    rfragsA(0);

#define BG_STAGE(S, CB, PB)                                                   \
    {                                                                         \
        bf16x8 b0 = PB[0], b1 = PB[1], b2 = PB[2];                            \
        if ((S) + 1 < nk2) lwriteA((CB) ^ 1);       /* pa holds stage S+1 */  \
        if ((S) + 2 < nk2) {                                                  \
            gloadA((S) + 2);                                                  \
            gloadB((S) + 2, PB);                                              \
        }                                                                     \
        _Pragma("unroll")                                                     \
        for (int i = 0; i < 4; i++)                                           \
            acc[i] = __builtin_amdgcn_mfma_f32_32x32x16_bf16(af[i], b0, acc[i], 0, 0, 0); \
        _Pragma("unroll")                                                     \
        for (int i = 0; i < 4; i++)                                           \
            acc[i] = __builtin_amdgcn_mfma_f32_32x32x16_bf16(af[i], b1, acc[i], 0, 0, 0); \
        _Pragma("unroll")                                                     \
        for (int i = 0; i < 4; i++)                                           \
            acc[i] = __builtin_amdgcn_mfma_f32_32x32x16_bf16(af[i], b2, acc[i], 0, 0, 0); \
        if ((S) + 1 < nk2) { __syncthreads(); rfragsA((CB) ^ 1); }            \
    }

    for (int s = 0; s < nk2; s += 2) {
        BG_STAGE(s, 0, pb0);
        BG_STAGE(s + 1, 1, pb1);
    }
#undef BG_STAGE

    // ---- in-block k-group reduction: acc_total = acc_g0 + acc_g1 ----
    // LDS reuse: 4 waves x 64 lanes x 16 f32 = 16 KB per m-tile pass.
    float* shf = (float*)shA;
#pragma unroll
    for (int i = 0; i < 4; i++) {
        __syncthreads();
        if (g == 1) {
#pragma unroll
            for (int r = 0; r < 16; r++)
                shf[sn * 1024 + r * 64 + L] = acc[i][r];
        }
        __syncthreads();
        if (g == 0) {
#pragma unroll
            for (int r = 0; r < 16; r++)
                acc[i][r] += shf[sn * 1024 + r * 64 + L];
        }
    }

    if (g == 0) {
        // C write: 32x32 tiles.  col = lane&31, row = (r&3)+8*(r>>2)+4*(lane>>5)
        float* Cp = C + (size_t)blockIdx.z * ((size_t)MROWS * N);
        const int col = L & 31, rbase = 4 * (L >> 5);
#pragma unroll
        for (int i = 0; i < 4; i++) {
            size_t tb = ((size_t)(bm32 + i) * NT + (bn32 + sn)) * 1024;
#pragma unroll
            for (int r = 0; r < 16; r++) {
                int row = (r & 3) + 8 * (r >> 2) + rbase;
                Cp[tb + row * 32 + col] = acc[i][r];
            }
        }
    }
}

// ---------------------------------------------------------------------------
// Legacy fp32 path (round-3, proven) for small workspace.
// ---------------------------------------------------------------------------
__global__ __launch_bounds__(256) void if_filter_kernel(
    float* __restrict__ buf, size_t partStride, int nparts,
    const float* __restrict__ w_sf, int F)
{
    int tid = blockIdx.x * 256 + threadIdx.x;
    const int NF = NB * F;
    bool  filt = (w_sf != nullptr);
    float d = filt ? sig_decay(w_sf) : 0.0f;
    float v = 0.f, u = 0.f;
    for (int t = 0; t < T_STEPS; t++) {
        size_t off = (size_t)t * NF + tid;
        float zt = buf[off];
        for (int p = 1; p < nparts; p++) zt += buf[p * partStride + off];
        v += zt;
        bool sp = v >= 1.0f;
        v = sp ? 0.0f : v;
        float s = sp ? 1.0f : 0.0f;
        if (filt) { u = u * d + s; buf[off] = u; }
        else      { buf[off] = s; }
    }
}

__global__ __launch_bounds__(256) void gemm_nt(
    const float* __restrict__ A, const float* __restrict__ B,
    float* __restrict__ C, int M, int N, int K_total, int K_per)
{
    constexpr int BM = 64, BN = 64, BK = 32;
    __shared__ float As[BK][BM + 4];
    __shared__ float Bs[BK][BN + 4];
    const int tid = threadIdx.x;
    const int tx  = tid & 15;
    const int ty  = tid >> 4;
    const int bm  = blockIdx.y * BM;
    const int bn  = blockIdx.x * BN;
    const int kbeg = blockIdx.z * K_per;
    float acc[4][4];
#pragma unroll
    for (int i = 0; i < 4; i++)
#pragma unroll
        for (int j = 0; j < 4; j++) acc[i][j] = 0.f;
    const int lrow = tid >> 3;
    const int lkq  = tid & 7;
    for (int kt = 0; kt < K_per; kt += BK) {
        int k0 = kbeg + kt;
        __syncthreads();
#pragma unroll
        for (int i = 0; i < 2; i++) {
            int row = lrow + i * 32;
            float4 av = *(const float4*)(A + (size_t)(bm + row) * K_total + k0 + lkq * 4);
            As[lkq * 4 + 0][row] = av.x;
            As[lkq * 4 + 1][row] = av.y;
            As[lkq * 4 + 2][row] = av.z;
            As[lkq * 4 + 3][row] = av.w;
            float4 bv = *(const float4*)(B + (size_t)(bn + row) * K_total + k0 + lkq * 4);
            Bs[lkq * 4 + 0][row] = bv.x;
            Bs[lkq * 4 + 1][row] = bv.y;
            Bs[lkq * 4 + 2][row] = bv.z;
            Bs[lkq * 4 + 3][row] = bv.w;
        }
        __syncthreads();
#pragma unroll
        for (int kk = 0; kk < BK; kk++) {
            float4 a0 = *(const float4*)&As[kk][ty * 4];
            float4 b0 = *(const float4*)&Bs[kk][tx * 4];
            float ar[4] = {a0.x, a0.y, a0.z, a0.w};
            float br[4] = {b0.x, b0.y, b0.z, b0.w};
#pragma unroll
            for (int i = 0; i < 4; i++)
#pragma unroll
                for (int j = 0; j < 4; j++) acc[i][j] += ar[i] * br[j];
        }
    }
    float* Cp = C + (size_t)blockIdx.z * (size_t)M * N;
#pragma unroll
    for (int i = 0; i < 4; i++) {
        float4 o;
        o.x = acc[i][0]; o.y = acc[i][1]; o.z = acc[i][2]; o.w = acc[i][3];
        *(float4*)(Cp + (size_t)(bm + ty * 4 + i) * N + bn + tx * 4) = o;
    }
}

// ---------------------------------------------------------------------------
// Final: out[t,n] = cumsum_t( dot(s3[t,n,:512], W_out) + b ).  One wave per n.
// ---------------------------------------------------------------------------
__global__ __launch_bounds__(64) void final_kernel(
    const float* __restrict__ y15, const float* __restrict__ W_out,
    const float* __restrict__ b_out, float* __restrict__ out)
{
    int n = blockIdx.x;
    int lane = threadIdx.x;
    float w[8];
#pragma unroll
    for (int j = 0; j < 8; j++) w[j] = W_out[lane + j * 64];
    float b = b_out[0];
    float cum = 0.f;
    for (int t = 0; t < T_STEPS; t++) {
        const float* yp = y15 + (size_t)(t * NB + n) * 512;
        float p = 0.f;
#pragma unroll
        for (int j = 0; j < 8; j++) p += yp[lane + j * 64] * w[j];
#pragma unroll
        for (int off = 32; off > 0; off >>= 1) p += __shfl_down(p, off);
        if (lane == 0) {
            cum += p + b;
            out[t * NB + n] = cum;
        }
    }
}

extern "C" void kernel_launch(void* const* d_in, const int* in_sizes, int n_in,
                              void* d_out, int out_size, void* d_ws, size_t ws_size,
                              hipStream_t stream) {
    (void)in_sizes; (void)n_in; (void)out_size;
    const float* x      = (const float*)d_in[0];
    const float* w_jeff = (const float*)d_in[1];
    const float* w_cc   = (const float*)d_in[2];
    const float* w_sf0  = (const float*)d_in[3];
    const float* W1     = (const float*)d_in[4];
    const float* w_sf1  = (const float*)d_in[5];
    const float* W2     = (const float*)d_in[6];
    const float* w_sf2  = (const float*)d_in[7];
    const float* W3     = (const float*)d_in[8];
    const float* w_sf3  = (const float*)d_in[9];
    const float* W_out  = (const float*)d_in[10];
    const float* b_out  = (const float*)d_in[11];
    float* out = (float*)d_out;
    const int M = MROWS;   // 2048

    const size_t nW1 = NW1, nW2 = NW2, nW3 = NW3;
    size_t need = 3 * (nW1 + nW2 + nW3) * 2     // packed planes   21 MB
                + (size_t)M * 512 * 2           // s6 packed        2 MB
                + (size_t)M * 2048 * 4          // G shared region 16 MB
                + (size_t)M * 2048 * 2          // s8               8 MB
                + (size_t)M * 1024 * 2          // s10              4 MB
                + (size_t)M * 512 * 4;          // s12              4 MB

    if (ws_size >= need) {
        unsigned short* Bp1 = (unsigned short*)d_ws;
        unsigned short* Bp2 = Bp1 + 3 * nW1;
        unsigned short* Bp3 = Bp2 + 3 * nW2;
        unsigned short* s6  = Bp3 + 3 * nW3;
        float* G   = (float*)(s6 + (size_t)M * 512);          // M*2048 floats
        unsigned short* s8  = (unsigned short*)(G + (size_t)M * 2048);
        unsigned short* s10 = s8 + (size_t)M * 2048;
        float* s12 = (float*)(s10 + (size_t)M * 1024);

        pack_all_kernel<<<(int)((nW1 + nW2 + nW3 + 255) / 256), 256, 0, stream>>>(
            W1, W2, W3, Bp1, Bp2, Bp3);

        front_kernel<<<NB * CC / 256, 256, 0, stream>>>(
            x, w_jeff, w_cc, w_sf0, w_sf1, s6, nullptr);

        // GEMM1: N=2048, K=512, sk=1 (in-block x2).  grid(16,16,1) = 256 blocks
        bgemm<<<dim3(16, 16, 1), 512, 0, stream>>>(s6, Bp1, G, 2048, 512, 512);
        if_spike_kernel<1><<<NB * 2048 / 256, 256, 0, stream>>>(
            G, 0, w_sf1, 2048, 11, s8, nullptr);

        // GEMM2: N=1024, K=2048, sk=2 (in-block x2).  grid(16,8,2) = 256 blocks
        bgemm<<<dim3(16, 8, 2), 512, 0, stream>>>(s8, Bp2, G, 1024, 2048, 1024);
        if_spike_kernel<2><<<NB * 1024 / 256, 256, 0, stream>>>(
            G, (size_t)M * 1024, w_sf2, 1024, 10, s10, nullptr);

        // GEMM3: N=512, K=1024, sk=4 (in-block x2).  grid(16,4,4) = 256 blocks
        bgemm<<<dim3(16, 4, 4), 512, 0, stream>>>(s10, Bp3, G, 512, 1024, 256);
        if_spike_kernel<4><<<NB * 512 / 256, 256, 0, stream>>>(
            G, (size_t)M * 512, w_sf3, 512, 9, nullptr, s12);

        final_kernel<<<NB, 64, 0, stream>>>(s12, W_out, b_out, out);
    } else {
        // ---------------- legacy fp32 path (round-3) ----------------
        float* y7  = (float*)d_ws;
        float* z1  = y7 + (size_t)M * 512;
        float* z2p = z1 + (size_t)M * 2048;
        float* z3p = z1;
        size_t need2 = ((size_t)M * 512 + (size_t)M * 2048 + 2 * (size_t)M * 1024) * 4;
        const int ksplit2 = (ws_size >= need2) ? 2 : 1;

        front_kernel<<<NB * CC / 256, 256, 0, stream>>>(
            x, w_jeff, w_cc, w_sf0, w_sf1, nullptr, y7);
        gemm_nt<<<dim3(2048 / 64, 2048 / 64, 1), 256, 0, stream>>>(
            y7, W1, z1, M, 2048, 512, 512);
        if_filter_kernel<<<NB * 2048 / 256, 256, 0, stream>>>(z1, 0, 1, w_sf2, 2048);
        gemm_nt<<<dim3(1024 / 64, 2048 / 64, ksplit2), 256, 0, stream>>>(
            z1, W2, z2p, M, 1024, 2048, 2048 / ksplit2);
        if_filter_kernel<<<NB * 1024 / 256, 256, 0, stream>>>(
            z2p, (size_t)M * 1024, ksplit2, w_sf3, 1024);
        gemm_nt<<<dim3(512 / 64, 2048 / 64, 4), 256, 0, stream>>>(
            z2p, W3, z3p, M, 512, 1024, 1024 / 4);
        if_filter_kernel<<<NB * 512 / 256, 256, 0, stream>>>(
            z3p, (size_t)M * 512, 4, nullptr, 512);
        final_kernel<<<NB, 64, 0, stream>>>(z3p, W_out, b_out, out);
    }
}